// Round 1
// baseline (409.743 us; speedup 1.0000x reference)
//
#include <hip/hip_runtime.h>
#include <hip/hip_bf16.h>
#include <stdint.h>

// GRU cell: B=16384, I=H=1024.
// z = sig(x@Wiz^T + h@Whz^T + bz), r = sig(x@Wir^T + h@Whr^T + br)
// g = tanh(x@Wih^T + bih + r*(h@Whh^T + bhh)); h' = (1-z)g + z h
// Strategy: bf16 MFMA fused GEMM, 4 accumulator sets (Z,R,GX,GH), K=2048 virtual [x|h].

#define BM 128
#define BN 128
#define BK 64
#define THREADS 512

typedef __bf16 bf16_t;
typedef __bf16 bf16x8 __attribute__((ext_vector_type(8)));
typedef float f32x4 __attribute__((ext_vector_type(4)));

// workspace layout in bf16 elements
#define XOFF 0
#define HOFF 16777216            // 16384*1024
#define WOFF 33554432            // x + h
#define WSZ  1048576             // 1024*1024
#define TOTAL_ELEMS 39845888     // 2*16777216 + 6*1048576

__device__ __forceinline__ void gload16(const void* g, void* l) {
  __builtin_amdgcn_global_load_lds(
      (const __attribute__((address_space(1))) void*)g,
      (__attribute__((address_space(3))) void*)l, 16, 0, 0);
}

__device__ __forceinline__ float fast_sigmoid(float v) {
  return 1.0f / (1.0f + __expf(-v));
}
__device__ __forceinline__ float fast_tanh(float v) {
  float e = __expf(-2.0f * fabsf(v));
  float t = (1.0f - e) / (1.0f + e);
  return v < 0.0f ? -t : t;
}

// fp32 -> bf16 conversion of x, h_prev, and 6 weight matrices into ws
__global__ __launch_bounds__(256) void convert_bf16(
    const float* __restrict__ x, const float* __restrict__ h,
    const float* __restrict__ wiz, const float* __restrict__ wir,
    const float* __restrict__ wih, const float* __restrict__ whz,
    const float* __restrict__ whr, const float* __restrict__ whh,
    bf16_t* __restrict__ ws)
{
  const long total8 = TOTAL_ELEMS / 8;
  long i = (long)blockIdx.x * blockDim.x + threadIdx.x;
  const long stride = (long)gridDim.x * blockDim.x;
  for (; i < total8; i += stride) {
    long e = i * 8;
    const float* src;
    if (e < HOFF) src = x + e;
    else if (e < WOFF) src = h + (e - HOFF);
    else {
      long r = e - WOFF;
      int wi = (int)(r >> 20);
      long off = r & (WSZ - 1);
      const float* wp = (wi == 0) ? wiz : (wi == 1) ? wir : (wi == 2) ? wih
                       : (wi == 3) ? whz : (wi == 4) ? whr : whh;
      src = wp + off;
    }
    float4 v0 = *(const float4*)src;
    float4 v1 = *(const float4*)(src + 4);
    bf16x8 o;
    o[0] = (__bf16)v0.x; o[1] = (__bf16)v0.y; o[2] = (__bf16)v0.z; o[3] = (__bf16)v0.w;
    o[4] = (__bf16)v1.x; o[5] = (__bf16)v1.y; o[6] = (__bf16)v1.z; o[7] = (__bf16)v1.w;
    *(bf16x8*)(ws + e) = o;
  }
}

// Fused GRU GEMM. Grid: 1024 blocks (128 m-blocks x 8 n-blocks), 512 threads.
// Per block: C tile 128x128; 8 waves (2 Mx4 N), per wave 64x32.
// K loop: t=0..15 over x (Wiz,Wir,Wih), t=16..31 over h (Whz,Whr,Whh).
__global__ __launch_bounds__(THREADS, 2) void gru_gemm(
    const bf16_t* __restrict__ ws,
    const float* __restrict__ h_prev,
    const float* __restrict__ biz, const float* __restrict__ bir,
    const float* __restrict__ bih, const float* __restrict__ bhz,
    const float* __restrict__ bhr, const float* __restrict__ bhh,
    float* __restrict__ out)
{
  extern __shared__ char smem[];  // 2 buffers x 64KB: [A 16K][W0 16K][W1 16K][W2 16K]
  const int tid = threadIdx.x;
  const int lane = tid & 63;
  const int wv = tid >> 6;        // wave 0..7
  const int wr = wv >> 2;         // 0..1  (wave row -> 64 rows)
  const int wc = wv & 3;          // 0..3  (wave col -> 32 cols)
  const int l15 = lane & 15, l4 = lane >> 4;

  // XCD swizzle: blocks id%8 -> XCD id%8; each XCD owns one n-panel (weights L2-resident)
  const int id = blockIdx.x;
  const int swz = (id & 7) * 128 + (id >> 3);
  const int m0 = (swz & 127) * BM;
  const int n0 = (swz >> 7) * BN;

  const bf16_t* xbf  = ws + XOFF;
  const bf16_t* hbf  = ws + HOFF;
  const bf16_t* wizp = ws + WOFF + 0 * WSZ;
  const bf16_t* wirp = ws + WOFF + 1 * WSZ;
  const bf16_t* wihp = ws + WOFF + 2 * WSZ;
  const bf16_t* whzp = ws + WOFF + 3 * WSZ;
  const bf16_t* whrp = ws + WOFF + 4 * WSZ;
  const bf16_t* whhp = ws + WOFF + 5 * WSZ;

  // ---- staging (global_load_lds, linear LDS dest; swizzle applied on global src) ----
  // linear byte off per round = tid*16 -> row = tid>>3 (0..63), kbyte = (tid&7)<<4
  // XOR swizzle (T2): lds[row][kb] holds global k-bytes (kb ^ ((row&7)<<4))
  const int rrow = tid >> 3;
  const int ksrc_e = (((tid & 7) ^ (rrow & 7)) << 3);   // element offset in row
  const size_t aoff0 = (size_t)(m0 + rrow) * 1024 + ksrc_e;
  const size_t woff0 = (size_t)(n0 + rrow) * 1024 + ksrc_e;
  const int wlds = wv * 1024;     // wave-uniform LDS base within an 8KB round

  // ---- ds_read fragment offsets (swizzled read matches source pre-swizzle) ----
  int aoffs[4][2], woffs[2][2];
  #pragma unroll
  for (int mi = 0; mi < 4; ++mi) {
    int row = wr * 64 + mi * 16 + l15;
    int sw = (row & 7) << 4;
    #pragma unroll
    for (int ks = 0; ks < 2; ++ks) {
      int kb = ks * 64 + l4 * 16;
      aoffs[mi][ks] = row * 128 + (kb ^ sw);
    }
  }
  #pragma unroll
  for (int ni = 0; ni < 2; ++ni) {
    int row = wc * 32 + ni * 16 + l15;
    int sw = (row & 7) << 4;
    #pragma unroll
    for (int ks = 0; ks < 2; ++ks) {
      int kb = ks * 64 + l4 * 16;
      woffs[ni][ks] = row * 128 + (kb ^ sw);
    }
  }

  f32x4 accZ[4][2], accR[4][2], accGX[4][2], accGH[4][2];
  const f32x4 zero = {0.f, 0.f, 0.f, 0.f};
  #pragma unroll
  for (int mi = 0; mi < 4; ++mi)
    #pragma unroll
    for (int ni = 0; ni < 2; ++ni) {
      accZ[mi][ni] = zero; accR[mi][ni] = zero;
      accGX[mi][ni] = zero; accGH[mi][ni] = zero;
    }

  auto stage = [&](int bufp, int t) {
    const int kk = (t * BK) & 1023;
    const bool xh = (t < 16);
    const bf16_t* As = xh ? xbf : hbf;
    const bf16_t* W0 = xh ? wizp : whzp;
    const bf16_t* W1 = xh ? wirp : whrp;
    const bf16_t* W2 = xh ? wihp : whhp;
    char* base = smem + bufp * 65536;
    gload16(As + aoff0 + kk,         base + 0     + wlds);
    gload16(As + aoff0 + kk + 65536, base + 8192  + wlds);  // rows 64..127
    gload16(W0 + woff0 + kk,         base + 16384 + wlds);
    gload16(W0 + woff0 + kk + 65536, base + 24576 + wlds);
    gload16(W1 + woff0 + kk,         base + 32768 + wlds);
    gload16(W1 + woff0 + kk + 65536, base + 40960 + wlds);
    gload16(W2 + woff0 + kk,         base + 49152 + wlds);
    gload16(W2 + woff0 + kk + 65536, base + 57344 + wlds);
  };

  auto compute = [&](int bufp, f32x4 (&accG)[4][2]) {
    const char* lb = smem + bufp * 65536;
    #pragma unroll
    for (int ks = 0; ks < 2; ++ks) {
      bf16x8 a[4], b0[2], b1[2], b2[2];
      #pragma unroll
      for (int mi = 0; mi < 4; ++mi)
        a[mi] = *(const bf16x8*)(lb + aoffs[mi][ks]);
      #pragma unroll
      for (int ni = 0; ni < 2; ++ni) {
        b0[ni] = *(const bf16x8*)(lb + 16384 + woffs[ni][ks]);
        b1[ni] = *(const bf16x8*)(lb + 32768 + woffs[ni][ks]);
        b2[ni] = *(const bf16x8*)(lb + 49152 + woffs[ni][ks]);
      }
      #pragma unroll
      for (int mi = 0; mi < 4; ++mi)
        #pragma unroll
        for (int ni = 0; ni < 2; ++ni) {
          accZ[mi][ni] = __builtin_amdgcn_mfma_f32_16x16x32_bf16(a[mi], b0[ni], accZ[mi][ni], 0, 0, 0);
          accR[mi][ni] = __builtin_amdgcn_mfma_f32_16x16x32_bf16(a[mi], b1[ni], accR[mi][ni], 0, 0, 0);
          accG[mi][ni] = __builtin_amdgcn_mfma_f32_16x16x32_bf16(a[mi], b2[ni], accG[mi][ni], 0, 0, 0);
        }
    }
  };

  int buf = 0;
  stage(0, 0);
  __syncthreads();
  #pragma unroll 1
  for (int t = 0; t < 16; ++t) {      // x half -> accGX
    stage(buf ^ 1, t + 1);
    compute(buf, accGX);
    __syncthreads();
    buf ^= 1;
  }
  #pragma unroll 1
  for (int t = 16; t < 32; ++t) {     // h half -> accGH
    if (t + 1 < 32) stage(buf ^ 1, t + 1);
    compute(buf, accGH);
    __syncthreads();
    buf ^= 1;
  }

  // ---- epilogue: bias + GRU nonlinearity + blend; C/D: col=lane&15, row=(lane>>4)*4+j ----
  #pragma unroll
  for (int ni = 0; ni < 2; ++ni) {
    const int n_g = n0 + wc * 32 + ni * 16 + l15;
    const float bz  = biz[n_g] + bhz[n_g];
    const float br  = bir[n_g] + bhr[n_g];
    const float bgx = bih[n_g];
    const float bgh = bhh[n_g];
    #pragma unroll
    for (int mi = 0; mi < 4; ++mi) {
      const int mrow = m0 + wr * 64 + mi * 16 + l4 * 4;
      #pragma unroll
      for (int j = 0; j < 4; ++j) {
        const size_t idx = (size_t)(mrow + j) * 1024 + n_g;
        const float z = fast_sigmoid(accZ[mi][ni][j] + bz);
        const float r = fast_sigmoid(accR[mi][ni][j] + br);
        const float g = fast_tanh(accGX[mi][ni][j] + bgx + r * (accGH[mi][ni][j] + bgh));
        out[idx] = (1.0f - z) * g + z * h_prev[idx];
      }
    }
  }
}

extern "C" void kernel_launch(void* const* d_in, const int* in_sizes, int n_in,
                              void* d_out, int out_size, void* d_ws, size_t ws_size,
                              hipStream_t stream) {
  (void)in_sizes; (void)n_in; (void)out_size; (void)ws_size;
  const float* x     = (const float*)d_in[0];
  const float* hprev = (const float*)d_in[1];
  const float* Wiz_w = (const float*)d_in[2];
  const float* Wiz_b = (const float*)d_in[3];
  const float* Wir_w = (const float*)d_in[4];
  const float* Wir_b = (const float*)d_in[5];
  const float* Wih_w = (const float*)d_in[6];
  const float* Wih_b = (const float*)d_in[7];
  const float* Whz_w = (const float*)d_in[8];
  const float* Whz_b = (const float*)d_in[9];
  const float* Whr_w = (const float*)d_in[10];
  const float* Whr_b = (const float*)d_in[11];
  const float* Whh_w = (const float*)d_in[12];
  const float* Whh_b = (const float*)d_in[13];
  float* out = (float*)d_out;
  bf16_t* ws = (bf16_t*)d_ws;

  hipFuncSetAttribute(reinterpret_cast<const void*>(gru_gemm),
                      hipFuncAttributeMaxDynamicSharedMemorySize, 131072);

  convert_bf16<<<2048, 256, 0, stream>>>(x, hprev, Wiz_w, Wir_w, Wih_w,
                                         Whz_w, Whr_w, Whh_w, ws);
  gru_gemm<<<1024, THREADS, 131072, stream>>>(ws, hprev, Wiz_b, Wir_b, Wih_b,
                                              Whz_b, Whr_b, Whh_b, out);
}

// Round 2
// 407.152 us; speedup vs baseline: 1.0064x; 1.0064x over previous
//
#include <hip/hip_runtime.h>
#include <hip/hip_bf16.h>
#include <stdint.h>

// GRU cell: B=16384, I=H=1024.
// z = sig(x@Wiz^T + h@Whz^T + bz), r = sig(x@Wir^T + h@Whr^T + br)
// g = tanh(x@Wih^T + bih + r*(h@Whh^T + bhh)); h' = (1-z)g + z h
// bf16 MFMA fused GEMM, 4 accumulator sets (Z,R,GX,GH), K=2048 virtual [x|h].
// R2: 3-phase K-step with counted vmcnt (T3/T4) + setprio (T5), raw barriers.

#define BM 128
#define BN 128
#define BK 64
#define THREADS 512

typedef __bf16 bf16_t;
typedef __bf16 bf16x8 __attribute__((ext_vector_type(8)));
typedef float f32x4 __attribute__((ext_vector_type(4)));

// workspace layout in bf16 elements
#define XOFF 0
#define HOFF 16777216            // 16384*1024
#define WOFF 33554432            // x + h
#define WSZ  1048576             // 1024*1024
#define TOTAL_ELEMS 39845888     // 2*16777216 + 6*1048576

__device__ __forceinline__ void gload16(const void* g, void* l) {
  __builtin_amdgcn_global_load_lds(
      (const __attribute__((address_space(1))) void*)g,
      (__attribute__((address_space(3))) void*)l, 16, 0, 0);
}

__device__ __forceinline__ float fast_sigmoid(float v) {
  return 1.0f / (1.0f + __expf(-v));
}
__device__ __forceinline__ float fast_tanh(float v) {
  float e = __expf(-2.0f * fabsf(v));
  float t = (1.0f - e) / (1.0f + e);
  return v < 0.0f ? -t : t;
}

// fp32 -> bf16 conversion of x, h_prev, and 6 weight matrices into ws
__global__ __launch_bounds__(256) void convert_bf16(
    const float* __restrict__ x, const float* __restrict__ h,
    const float* __restrict__ wiz, const float* __restrict__ wir,
    const float* __restrict__ wih, const float* __restrict__ whz,
    const float* __restrict__ whr, const float* __restrict__ whh,
    bf16_t* __restrict__ ws)
{
  const long total8 = TOTAL_ELEMS / 8;
  long i = (long)blockIdx.x * blockDim.x + threadIdx.x;
  const long stride = (long)gridDim.x * blockDim.x;
  for (; i < total8; i += stride) {
    long e = i * 8;
    const float* src;
    if (e < HOFF) src = x + e;
    else if (e < WOFF) src = h + (e - HOFF);
    else {
      long r = e - WOFF;
      int wi = (int)(r >> 20);
      long off = r & (WSZ - 1);
      const float* wp = (wi == 0) ? wiz : (wi == 1) ? wir : (wi == 2) ? wih
                       : (wi == 3) ? whz : (wi == 4) ? whr : whh;
      src = wp + off;
    }
    float4 v0 = *(const float4*)src;
    float4 v1 = *(const float4*)(src + 4);
    bf16x8 o;
    o[0] = (__bf16)v0.x; o[1] = (__bf16)v0.y; o[2] = (__bf16)v0.z; o[3] = (__bf16)v0.w;
    o[4] = (__bf16)v1.x; o[5] = (__bf16)v1.y; o[6] = (__bf16)v1.z; o[7] = (__bf16)v1.w;
    *(bf16x8*)(ws + e) = o;
  }
}

// Fused GRU GEMM. Grid: 1024 blocks (128 m-blocks x 8 n-blocks), 512 threads.
__global__ __launch_bounds__(THREADS, 2) void gru_gemm(
    const bf16_t* __restrict__ ws,
    const float* __restrict__ h_prev,
    const float* __restrict__ biz, const float* __restrict__ bir,
    const float* __restrict__ bih, const float* __restrict__ bhz,
    const float* __restrict__ bhr, const float* __restrict__ bhh,
    float* __restrict__ out)
{
  extern __shared__ char smem[];  // 2 buffers x 64KB: [A 16K][W0 16K][W1 16K][W2 16K]
  const int tid = threadIdx.x;
  const int lane = tid & 63;
  const int wv = tid >> 6;        // wave 0..7
  const int wr = wv >> 2;         // 0..1
  const int wc = wv & 3;          // 0..3
  const int l15 = lane & 15, l4 = lane >> 4;

  // XCD swizzle: each XCD (id%8) owns one n-panel (weights stay L2-resident)
  const int id = blockIdx.x;
  const int swz = (id & 7) * 128 + (id >> 3);
  const int m0 = (swz & 127) * BM;
  const int n0 = (swz >> 7) * BN;

  const bf16_t* xbf  = ws + XOFF;
  const bf16_t* hbf  = ws + HOFF;
  const bf16_t* wizp = ws + WOFF + 0 * WSZ;
  const bf16_t* wirp = ws + WOFF + 1 * WSZ;
  const bf16_t* wihp = ws + WOFF + 2 * WSZ;
  const bf16_t* whzp = ws + WOFF + 3 * WSZ;
  const bf16_t* whrp = ws + WOFF + 4 * WSZ;
  const bf16_t* whhp = ws + WOFF + 5 * WSZ;

  // staging: linear LDS dest (tid*16 per round); T2 swizzle applied on global src
  const int rrow = tid >> 3;
  const int ksrc_e = (((tid & 7) ^ (rrow & 7)) << 3);
  const size_t aoff0 = (size_t)(m0 + rrow) * 1024 + ksrc_e;
  const size_t woff0 = (size_t)(n0 + rrow) * 1024 + ksrc_e;
  const int wlds = wv * 1024;

  // swizzled ds_read fragment offsets
  int aoffs[4][2], woffs[2][2];
  #pragma unroll
  for (int mi = 0; mi < 4; ++mi) {
    int row = wr * 64 + mi * 16 + l15;
    int sw = (row & 7) << 4;
    #pragma unroll
    for (int ks = 0; ks < 2; ++ks)
      aoffs[mi][ks] = row * 128 + ((ks * 64 + l4 * 16) ^ sw);
  }
  #pragma unroll
  for (int ni = 0; ni < 2; ++ni) {
    int row = wc * 32 + ni * 16 + l15;
    int sw = (row & 7) << 4;
    #pragma unroll
    for (int ks = 0; ks < 2; ++ks)
      woffs[ni][ks] = row * 128 + ((ks * 64 + l4 * 16) ^ sw);
  }

  f32x4 accZ[4][2], accR[4][2], accGX[4][2], accGH[4][2];
  const f32x4 zero = {0.f, 0.f, 0.f, 0.f};
  #pragma unroll
  for (int mi = 0; mi < 4; ++mi)
    #pragma unroll
    for (int ni = 0; ni < 2; ++ni) {
      accZ[mi][ni] = zero; accR[mi][ni] = zero;
      accGX[mi][ni] = zero; accGH[mi][ni] = zero;
    }

  auto srcs = [&](int t, const bf16_t*& As, const bf16_t*& W0,
                  const bf16_t*& W1, const bf16_t*& W2) {
    const bool xh = (t < 16);
    As = xh ? xbf : hbf;
    W0 = xh ? wizp : whzp;
    W1 = xh ? wirp : whrp;
    W2 = xh ? wihp : whhp;
  };
  // stage parts for tile t into buffer bufp (3 + 3 + 2 gloads; A first = longest latency)
  auto part0 = [&](int bufp, int t) {
    const int kk = (t * BK) & 1023;
    const bf16_t *As, *W0, *W1, *W2; srcs(t, As, W0, W1, W2);
    char* base = smem + bufp * 65536;
    gload16(As + aoff0 + kk,         base + 0     + wlds);
    gload16(As + aoff0 + kk + 65536, base + 8192  + wlds);
    gload16(W0 + woff0 + kk,         base + 16384 + wlds);
  };
  auto part1 = [&](int bufp, int t) {
    const int kk = (t * BK) & 1023;
    const bf16_t *As, *W0, *W1, *W2; srcs(t, As, W0, W1, W2);
    char* base = smem + bufp * 65536;
    gload16(W0 + woff0 + kk + 65536, base + 24576 + wlds);
    gload16(W1 + woff0 + kk,         base + 32768 + wlds);
    gload16(W1 + woff0 + kk + 65536, base + 40960 + wlds);
  };
  auto part2 = [&](int bufp, int t) {
    const int kk = (t * BK) & 1023;
    const bf16_t *As, *W0, *W1, *W2; srcs(t, As, W0, W1, W2);
    char* base = smem + bufp * 65536;
    gload16(W2 + woff0 + kk,         base + 49152 + wlds);
    gload16(W2 + woff0 + kk + 65536, base + 57344 + wlds);
  };

  // One K-step, 3 phases (Z | R | G), counted vmcnt, 2 raw barriers.
  auto kstep = [&](int t, f32x4 (&accG)[4][2], bool last) {
    const int c = t & 1;
    const char* lb = smem + c * 65536;
    // ---- P0: issue part0(t+1) [target buf c^1 — freed before prior free-barrier],
    //          wait own stage(t) (counted), visibility barrier, Z phase ----
    if (!last) {
      part0(c ^ 1, t + 1);
      asm volatile("s_waitcnt vmcnt(3)" ::: "memory");
    } else {
      asm volatile("s_waitcnt vmcnt(0)" ::: "memory");
    }
    __builtin_amdgcn_s_barrier();
    __builtin_amdgcn_sched_barrier(0);
    bf16x8 a[4][2];
    #pragma unroll
    for (int mi = 0; mi < 4; ++mi)
      #pragma unroll
      for (int ks = 0; ks < 2; ++ks)
        a[mi][ks] = *(const bf16x8*)(lb + aoffs[mi][ks]);
    {
      bf16x8 b[2][2];
      #pragma unroll
      for (int ni = 0; ni < 2; ++ni)
        #pragma unroll
        for (int ks = 0; ks < 2; ++ks)
          b[ni][ks] = *(const bf16x8*)(lb + 16384 + woffs[ni][ks]);
      __builtin_amdgcn_s_setprio(1);
      #pragma unroll
      for (int mi = 0; mi < 4; ++mi)
        #pragma unroll
        for (int ni = 0; ni < 2; ++ni)
          #pragma unroll
          for (int ks = 0; ks < 2; ++ks)
            accZ[mi][ni] = __builtin_amdgcn_mfma_f32_16x16x32_bf16(a[mi][ks], b[ni][ks], accZ[mi][ni], 0, 0, 0);
      __builtin_amdgcn_s_setprio(0);
    }
    // ---- P1: issue part1(t+1), R phase ----
    if (!last) part1(c ^ 1, t + 1);
    {
      bf16x8 b[2][2];
      #pragma unroll
      for (int ni = 0; ni < 2; ++ni)
        #pragma unroll
        for (int ks = 0; ks < 2; ++ks)
          b[ni][ks] = *(const bf16x8*)(lb + 32768 + woffs[ni][ks]);
      __builtin_amdgcn_s_setprio(1);
      #pragma unroll
      for (int mi = 0; mi < 4; ++mi)
        #pragma unroll
        for (int ni = 0; ni < 2; ++ni)
          #pragma unroll
          for (int ks = 0; ks < 2; ++ks)
            accR[mi][ni] = __builtin_amdgcn_mfma_f32_16x16x32_bf16(a[mi][ks], b[ni][ks], accR[mi][ni], 0, 0, 0);
      __builtin_amdgcn_s_setprio(0);
    }
    // ---- P2: issue part2(t+1), G phase, free-barrier ----
    if (!last) part2(c ^ 1, t + 1);
    {
      bf16x8 b[2][2];
      #pragma unroll
      for (int ni = 0; ni < 2; ++ni)
        #pragma unroll
        for (int ks = 0; ks < 2; ++ks)
          b[ni][ks] = *(const bf16x8*)(lb + 49152 + woffs[ni][ks]);
      __builtin_amdgcn_s_setprio(1);
      #pragma unroll
      for (int mi = 0; mi < 4; ++mi)
        #pragma unroll
        for (int ni = 0; ni < 2; ++ni)
          #pragma unroll
          for (int ks = 0; ks < 2; ++ks)
            accG[mi][ni] = __builtin_amdgcn_mfma_f32_16x16x32_bf16(a[mi][ks], b[ni][ks], accG[mi][ni], 0, 0, 0);
      __builtin_amdgcn_s_setprio(0);
    }
    __builtin_amdgcn_s_barrier();     // frees buf c for stage(t+2)
    __builtin_amdgcn_sched_barrier(0);
  };

  // prologue: full stage of tile 0 into buf 0
  part0(0, 0); part1(0, 0); part2(0, 0);
  #pragma unroll 1
  for (int t = 0; t < 16; ++t) kstep(t, accGX, false);     // x half
  #pragma unroll 1
  for (int t = 16; t < 32; ++t) kstep(t, accGH, t == 31);  // h half

  // ---- epilogue: bias + GRU nonlinearity + blend; C/D: col=lane&15, row=(lane>>4)*4+j ----
  #pragma unroll
  for (int ni = 0; ni < 2; ++ni) {
    const int n_g = n0 + wc * 32 + ni * 16 + l15;
    const float bz  = biz[n_g] + bhz[n_g];
    const float br  = bir[n_g] + bhr[n_g];
    const float bgx = bih[n_g];
    const float bgh = bhh[n_g];
    #pragma unroll
    for (int mi = 0; mi < 4; ++mi) {
      const int mrow = m0 + wr * 64 + mi * 16 + l4 * 4;
      #pragma unroll
      for (int j = 0; j < 4; ++j) {
        const size_t idx = (size_t)(mrow + j) * 1024 + n_g;
        const float z = fast_sigmoid(accZ[mi][ni][j] + bz);
        const float r = fast_sigmoid(accR[mi][ni][j] + br);
        const float g = fast_tanh(accGX[mi][ni][j] + bgx + r * (accGH[mi][ni][j] + bgh));
        out[idx] = (1.0f - z) * g + z * h_prev[idx];
      }
    }
  }
}

extern "C" void kernel_launch(void* const* d_in, const int* in_sizes, int n_in,
                              void* d_out, int out_size, void* d_ws, size_t ws_size,
                              hipStream_t stream) {
  (void)in_sizes; (void)n_in; (void)out_size; (void)ws_size;
  const float* x     = (const float*)d_in[0];
  const float* hprev = (const float*)d_in[1];
  const float* Wiz_w = (const float*)d_in[2];
  const float* Wiz_b = (const float*)d_in[3];
  const float* Wir_w = (const float*)d_in[4];
  const float* Wir_b = (const float*)d_in[5];
  const float* Wih_w = (const float*)d_in[6];
  const float* Wih_b = (const float*)d_in[7];
  const float* Whz_w = (const float*)d_in[8];
  const float* Whz_b = (const float*)d_in[9];
  const float* Whr_w = (const float*)d_in[10];
  const float* Whr_b = (const float*)d_in[11];
  const float* Whh_w = (const float*)d_in[12];
  const float* Whh_b = (const float*)d_in[13];
  float* out = (float*)d_out;
  bf16_t* ws = (bf16_t*)d_ws;

  hipFuncSetAttribute(reinterpret_cast<const void*>(gru_gemm),
                      hipFuncAttributeMaxDynamicSharedMemorySize, 131072);

  convert_bf16<<<2048, 256, 0, stream>>>(x, hprev, Wiz_w, Wir_w, Wih_w,
                                         Whz_w, Whr_w, Whh_w, ws);
  gru_gemm<<<1024, THREADS, 131072, stream>>>(ws, hprev, Wiz_b, Wir_b, Wih_b,
                                              Whz_b, Whr_b, Whh_b, out);
}